// Round 15
// baseline (274.736 us; speedup 1.0000x reference)
//
#include <hip/hip_runtime.h>

#define NN 50000
#define NE 800000
#define NCHK 200     // edge chunks (NCHK*CHKE == NE exactly)
#define CHKE 4000
#define NBUK 196     // dst>>8 buckets (50000/256 -> 196 covers 50176)
#define BCAP 5120    // per-bucket LDS capacity (mean 4082, sd 64 -> +16 sd)
#define NOFF (NBUK * NCHK)          // 39200
#define NSB  ((NOFF + 255) / 256)   // 154 scan blocks

typedef __attribute__((ext_vector_type(8))) short short8;
typedef __attribute__((ext_vector_type(4))) float f32x4;
typedef unsigned int u32;
typedef unsigned short u16;

__device__ __forceinline__ float bf2f(short u) {
    union { unsigned int i; float f; } c;
    c.i = ((unsigned int)(unsigned short)u) << 16;
    return c.f;
}
__device__ __forceinline__ short f2bf(float f) {
    union { float f; unsigned int i; } c; c.f = f;
    unsigned int u = c.i;
    unsigned int r = (u + 0x7FFFu + ((u >> 16) & 1u)) >> 16;
    return (short)r;
}

// ---------- small utility kernels ----------

__global__ void cvt_f32_bf16_kernel(const float* __restrict__ in, short* __restrict__ out, int n) {
    int gid = blockIdx.x * 256 + threadIdx.x;
    if (gid < n) out[gid] = f2bf(in[gid]);
}

// Weights -> bf16 blobs in REGISTER-FRAGMENT order (for direct coalesced VGPR loads):
// element (k,d):  kt=k>>6, ks=(k>>5)&1, kg=(k>>3)&3, j=k&7, cgp=d>>4, l=d&15
// off = ((((kt*2+ks)*(Dout/16) + cgp)*4 + kg)*16 + l)*8 + j
__global__ void wcvt_all_kernel(const float* __restrict__ Ws0, const float* __restrict__ Wn0,
                                const float* __restrict__ Ws1, const float* __restrict__ Wn1,
                                const float* __restrict__ Ws2, const float* __restrict__ Wn2,
                                short* __restrict__ wts) {
    int gid = blockIdx.x * 256 + threadIdx.x;   // 0..262143
    const float* W; int K, Dout, base, loc;
    if (gid < 65536)       { K = 128; Dout = 256; base = (gid < 32768)  ? 0 : 32768;
                             W = (gid < 32768)  ? Ws0 : Wn0; loc = gid & 32767; }
    else if (gid < 196608) { K = 256; Dout = 256; base = (gid < 131072) ? 65536 : 131072;
                             W = (gid < 131072) ? Ws1 : Wn1; loc = (gid - 65536) & 65535; }
    else                   { K = 256; Dout = 128; base = (gid < 229376) ? 196608 : 229376;
                             W = (gid < 229376) ? Ws2 : Wn2; loc = (gid - 196608) & 32767; }
    int k = loc / Dout, d = loc - k * Dout;
    int kt = k >> 6, ks = (k >> 5) & 1, kg = (k >> 3) & 3, j = k & 7;
    int cgp = d >> 4, l = d & 15;
    int off = ((((kt * 2 + ks) * (Dout >> 4) + cgp) * 4 + kg) * 16 + l) * 8 + j;
    wts[base + off] = f2bf(W[(long)k * Dout + d]);
}

// ---------- bucketed CSR build ----------
__global__ __launch_bounds__(256) void bucket_hist_kernel(const int* __restrict__ dst,
                                                          int* __restrict__ chist) {
    __shared__ int lh[NBUK];
    int b = blockIdx.x, t = threadIdx.x;
    for (int i = t; i < NBUK; i += 256) lh[i] = 0;
    __syncthreads();
    int base = b * CHKE;
    for (int i = t; i < CHKE; i += 256) atomicAdd(&lh[dst[base + i] >> 8], 1);
    __syncthreads();
    for (int i = t; i < NBUK; i += 256) chist[i * NCHK + b] = lh[i];
}

__global__ __launch_bounds__(256) void off_blocksum_kernel(const int* __restrict__ in,
                                                           int* __restrict__ bsum) {
    __shared__ int sm[256];
    int t = threadIdx.x;
    int idx = blockIdx.x * 256 + t;
    sm[t] = (idx < NOFF) ? in[idx] : 0;
    __syncthreads();
    for (int off = 128; off > 0; off >>= 1) {
        if (t < off) sm[t] += sm[t + off];
        __syncthreads();
    }
    if (t == 0) bsum[blockIdx.x] = sm[0];
}

__global__ __launch_bounds__(256) void off_scanb_kernel(const int* __restrict__ bsum,
                                                        int* __restrict__ bpre) {
    __shared__ int sm[256];
    int t = threadIdx.x;
    sm[t] = (t < NSB) ? bsum[t] : 0;
    __syncthreads();
    for (int o = 1; o < 256; o <<= 1) {
        int v = sm[t];
        int a = (t >= o) ? sm[t - o] : 0;
        __syncthreads();
        sm[t] = v + a;
        __syncthreads();
    }
    if (t < NSB) bpre[t] = (t == 0) ? 0 : sm[t - 1];
}

__global__ __launch_bounds__(256) void off_scatter_kernel(const int* __restrict__ in,
                                                          const int* __restrict__ bpre,
                                                          int* __restrict__ off) {
    __shared__ int sm[256];
    int t = threadIdx.x;
    int idx = blockIdx.x * 256 + t;
    int val = (idx < NOFF) ? in[idx] : 0;
    sm[t] = val;
    __syncthreads();
    for (int o = 1; o < 256; o <<= 1) {
        int v = sm[t];
        int a = (t >= o) ? sm[t - o] : 0;
        __syncthreads();
        sm[t] = v + a;
        __syncthreads();
    }
    if (idx < NOFF) off[idx] = bpre[blockIdx.x] + sm[t] - val;   // exclusive
}

__global__ __launch_bounds__(256) void bucket_scatter_kernel(const int* __restrict__ src,
                                                             const int* __restrict__ dst,
                                                             const int* __restrict__ off,
                                                             u32* __restrict__ ebuf) {
    __shared__ int lcur[NBUK];
    int b = blockIdx.x, t = threadIdx.x;
    for (int i = t; i < NBUK; i += 256) lcur[i] = off[i * NCHK + b];
    __syncthreads();
    int base = b * CHKE;
    for (int i = t; i < CHKE; i += 256) {
        int d = dst[base + i], s = src[base + i];
        int slot = atomicAdd(&lcur[d >> 8], 1);
        ebuf[slot] = ((u32)(d & 255) << 16) | (u32)s;
    }
}

__global__ __launch_bounds__(256) void bucket_sort_kernel(const u32* __restrict__ ebuf,
                                                          const int* __restrict__ off,
                                                          u16* __restrict__ srcs16,
                                                          int* __restrict__ row_start,
                                                          int* __restrict__ cnt) {
    __shared__ u32 earr[BCAP];
    __shared__ u16 s16[BCAP];
    __shared__ int lhist[256], lpre[256], lcur[256];
    int k = blockIdx.x, t = threadIdx.x;
    int base = off[k * NCHK];
    int end  = (k < NBUK - 1) ? off[(k + 1) * NCHK] : NE;
    int nE = end - base;
    lhist[t] = 0;
    __syncthreads();
    for (int i = t; i < nE; i += 256) {
        u32 e = ebuf[base + i];
        earr[i] = e;
        atomicAdd(&lhist[e >> 16], 1);
    }
    __syncthreads();
    int v = lhist[t];
    lpre[t] = v;
    __syncthreads();
    for (int o = 1; o < 256; o <<= 1) {
        int x = lpre[t];
        int a = (t >= o) ? lpre[t - o] : 0;
        __syncthreads();
        lpre[t] = x + a;
        __syncthreads();
    }
    int excl = lpre[t] - v;
    int node = k * 256 + t;
    if (node < NN) { row_start[node] = base + excl; cnt[node] = v; }
    lcur[t] = excl;
    __syncthreads();
    for (int i = t; i < nE; i += 256) {
        u32 e = earr[i];
        int pos = atomicAdd(&lcur[e >> 16], 1);
        s16[pos] = (u16)(e & 0xFFFFu);
    }
    __syncthreads();
    for (int i = t; i < nE; i += 256) srcs16[base + i] = s16[i];
}

// ---------- gather-mean: wave per node, EPL edges per load, 16B/lane ----------

template<int D>
__global__ __launch_bounds__(256) void gather_mean2_kernel(
    const short* __restrict__ h, const u16* __restrict__ srcs,
    const int* __restrict__ row_start, const int* __restrict__ cnt,
    short* __restrict__ nb)
{
    constexpr int CPR = D / 8;        // short8 groups per row (16 or 32)
    constexpr int EPL = 64 / CPR;     // edges per wave-load (4 or 2)
    const int wave = threadIdx.x >> 6;
    const int lane = threadIdx.x & 63;
    const int v = blockIdx.x * 4 + wave;
    if (v >= NN) return;
    const int c  = cnt[v];
    const int rs = row_start[v];
    const int slot = lane / CPR;
    const int cg   = lane & (CPR - 1);
    float acc[8];
    #pragma unroll
    for (int j = 0; j < 8; ++j) acc[j] = 0.f;
    const short8* hp = (const short8*)h;
    int i = slot;
    for (; i + 3 * EPL < c; i += 4 * EPL) {
        int s0 = srcs[rs + i];
        int s1 = srcs[rs + i + EPL];
        int s2 = srcs[rs + i + 2 * EPL];
        int s3 = srcs[rs + i + 3 * EPL];
        short8 v0 = hp[(size_t)s0 * CPR + cg];
        short8 v1 = hp[(size_t)s1 * CPR + cg];
        short8 v2 = hp[(size_t)s2 * CPR + cg];
        short8 v3 = hp[(size_t)s3 * CPR + cg];
        #pragma unroll
        for (int j = 0; j < 8; ++j)
            acc[j] += (bf2f(v0[j]) + bf2f(v1[j])) + (bf2f(v2[j]) + bf2f(v3[j]));
    }
    for (; i < c; i += EPL) {
        int s0 = srcs[rs + i];
        short8 v0 = hp[(size_t)s0 * CPR + cg];
        #pragma unroll
        for (int j = 0; j < 8; ++j) acc[j] += bf2f(v0[j]);
    }
    #pragma unroll
    for (int j = 0; j < 8; ++j) {
        if (EPL == 4) acc[j] += __shfl_xor(acc[j], 16);
        acc[j] += __shfl_xor(acc[j], 32);
    }
    if (slot == 0) {
        float inv = (c > 0) ? (1.0f / (float)c) : 0.0f;
        short8 outv;
        #pragma unroll
        for (int j = 0; j < 8; ++j) outv[j] = f2bf(acc[j] * inv);
        ((short8*)nb)[(size_t)v * CPR + cg] = outv;
    }
}

// ---------- fused SAGE layer GEMM v7: NO LDS, no barriers ----------
// out = act(A@B0^T [+ Aneigh@B1^T] + bias [+ addin])
// A-fragments loaded per-lane direct global->VGPR (intra-block duplication
// absorbed by L1/L2); W from reg-fragment blobs. Fully unrolled k-loop ->
// compiler software-pipelines loads freely; zero synchronization.
// 256 threads = 4 waves. NOUT=256: BM=64 (4 col-waves); NOUT=128: BM=128 (2x2).
template<int NOUT, int KK, int PHASES, bool RELU, bool OUT_F32, bool ADDIN, bool BIAS>
__global__ __launch_bounds__(256, 4) void gemm_sage7_kernel(
    const short* __restrict__ Aself, const short* __restrict__ Aneigh,
    const short* __restrict__ Bself, const short* __restrict__ Bneigh,
    const float* __restrict__ bias, void* __restrict__ outp, int M,
    const short* __restrict__ addin)
{
    constexpr int WN = NOUT / 64;          // col wave-groups (4 or 2)
    constexpr int WM = 4 / WN;             // row wave-groups (1 or 2)
    constexpr int BM = 64 * WM;            // 64 or 128
    constexpr int MR = 4;                  // 16-row frags per wave
    constexpr int NR = 4;                  // 16-col frags per wave
    constexpr int KT = KK / 64;            // k-tiles per operand
    constexpr int NT = PHASES * KT;        // total k-tiles
    constexpr int CG = NOUT / 16;          // col-groups in blob

    const int tid  = threadIdx.x;
    const int wave = tid >> 6;
    const int lane = tid & 63;
    const int wm = wave / WN;
    const int wn = wave % WN;
    const int l15 = lane & 15;
    const int kg  = lane >> 4;
    const int bm  = blockIdx.x * BM;

    f32x4 acc[MR][NR];
    #pragma unroll
    for (int a = 0; a < MR; ++a)
        #pragma unroll
        for (int b = 0; b < NR; ++b)
            acc[a][b] = (f32x4){0.f, 0.f, 0.f, 0.f};

    // per-thread A row pointers (row = bm + wm*64 + mr*16 + l15)
    const short* arow_s[MR];
    const short* arow_n[MR];
    #pragma unroll
    for (int mr = 0; mr < MR; ++mr) {
        size_t r = (size_t)(bm + wm * 64 + mr * 16 + l15) * KK;
        arow_s[mr] = Aself + r;
        arow_n[mr] = Aneigh + r;
    }

    #pragma unroll
    for (int t = 0; t < NT; ++t) {
        const int ph = t / KT, kt = t - ph * KT;
        const short* __restrict__ Wb = ph ? Bneigh : Bself;
        const int koff = kt * 64;
        #pragma unroll
        for (int ks = 0; ks < 2; ++ks) {
            short8 wreg[NR], areg[MR];
            #pragma unroll
            for (int nr = 0; nr < NR; ++nr)
                wreg[nr] = *(const short8*)(
                    Wb + (size_t)((((kt * 2 + ks) * CG + wn * NR + nr) * 4 + kg) * 16 + l15) * 8);
            #pragma unroll
            for (int mr = 0; mr < MR; ++mr)
                areg[mr] = *(const short8*)((ph ? arow_n[mr] : arow_s[mr]) + koff + ks * 32 + kg * 8);
            #pragma unroll
            for (int mr = 0; mr < MR; ++mr)
                #pragma unroll
                for (int nr = 0; nr < NR; ++nr)
                    acc[mr][nr] = __builtin_amdgcn_mfma_f32_16x16x32_bf16(
                        areg[mr], wreg[nr], acc[mr][nr], 0, 0, 0);
        }
    }

    // epilogue
    #pragma unroll
    for (int mr = 0; mr < MR; ++mr) {
        int rowb = bm + wm * 64 + mr * 16 + kg * 4;
        #pragma unroll
        for (int nr = 0; nr < NR; ++nr) {
            int col = wn * 64 + nr * 16 + l15;
            float bv = BIAS ? bias[col] : 0.f;
            #pragma unroll
            for (int r = 0; r < 4; ++r) {
                int row = rowb + r;
                if (row < M) {
                    float vv = acc[mr][nr][r] + bv;
                    if (ADDIN) vv += bf2f(addin[(size_t)row * NOUT + col]);
                    if (RELU) vv = fmaxf(vv, 0.f);
                    if (OUT_F32) ((float*)outp)[(size_t)row * NOUT + col] = vv;
                    else         ((short*)outp)[(size_t)row * NOUT + col] = f2bf(vv);
                }
            }
        }
    }
}

// ---------- launch ----------

extern "C" void kernel_launch(void* const* d_in, const int* in_sizes, int n_in,
                              void* d_out, int out_size, void* d_ws, size_t ws_size,
                              hipStream_t stream) {
    const float* x    = (const float*)d_in[0];
    const int*   srcp = (const int*)d_in[1];
    const int*   dstp = (const int*)d_in[2];
    const float* Ws0  = (const float*)d_in[3];
    const float* Wn0  = (const float*)d_in[4];
    const float* b0   = (const float*)d_in[5];
    const float* Ws1  = (const float*)d_in[6];
    const float* Wn1  = (const float*)d_in[7];
    const float* b1   = (const float*)d_in[8];
    const float* Ws2  = (const float*)d_in[9];
    const float* Wn2  = (const float*)d_in[10];
    const float* b2   = (const float*)d_in[11];

    char* base = (char*)d_ws;
    size_t off_b = 0;
    auto alloc = [&](size_t bytes) -> void* {
        void* p = base + off_b;
        off_b += (bytes + 255) & ~(size_t)255;
        return p;
    };

    int*   cnt       = (int*)alloc((size_t)NN * 4);
    int*   row_start = (int*)alloc((size_t)NN * 4);
    int*   chist     = (int*)alloc((size_t)NOFF * 4);
    int*   offb      = (int*)alloc((size_t)NOFF * 4);
    int*   bsum      = (int*)alloc((size_t)NSB * 4);
    int*   bpre      = (int*)alloc((size_t)NSB * 4);
    u32*   ebuf      = (u32*)alloc((size_t)NE * 4);
    u16*   srcs16    = (u16*)alloc((size_t)NE * 2);
    short* hA        = (short*)alloc((size_t)NN * 256 * 2);
    short* hB        = (short*)alloc((size_t)NN * 256 * 2);
    short* nb        = (short*)alloc((size_t)NN * 256 * 2);
    short* wts       = (short*)alloc((size_t)262144 * 2 + 131072);
    short* Wt0s = wts;            // blobs, see wcvt_all_kernel
    short* Wt0n = Wt0s + 32768;
    short* Wt1s = Wt0n + 32768;
    short* Wt1n = Wt1s + 65536;
    short* Wt2s = Wt1n + 65536;
    short* Wt2n = Wt2s + 32768;

    // CSR build: bucketed counting sort (XCD-local final scatter)
    bucket_hist_kernel<<<NCHK, 256, 0, stream>>>(dstp, chist);
    off_blocksum_kernel<<<NSB, 256, 0, stream>>>(chist, bsum);
    off_scanb_kernel<<<1, 256, 0, stream>>>(bsum, bpre);
    off_scatter_kernel<<<NSB, 256, 0, stream>>>(chist, bpre, offb);
    bucket_scatter_kernel<<<NCHK, 256, 0, stream>>>(srcp, dstp, offb, ebuf);
    bucket_sort_kernel<<<NBUK, 256, 0, stream>>>(ebuf, offb, srcs16, row_start, cnt);

    // weight conversion -> reg-fragment bf16 blobs, single launch
    wcvt_all_kernel<<<1024, 256, 0, stream>>>(Ws0, Wn0, Ws1, Wn1, Ws2, Wn2, wts);

    // x -> bf16
    cvt_f32_bf16_kernel<<<(NN * 128 + 255) / 256, 256, 0, stream>>>(x, hA, NN * 128);

    const int mblk64  = (NN + 63) / 64;     // 782 (NOUT=256 path, BM=64)
    const int mblk128 = (NN + 127) / 128;   // 391 (NOUT=128 path, BM=128)
    const int gblocks = (NN + 3) / 4;       // 12500

    // layer 0: h0 [N,128] -> h1 [N,256] (relu)   hB = relu(hA@Ws0 + gather(hA)@Wn0 + b0)
    gather_mean2_kernel<128><<<gblocks, 256, 0, stream>>>(hA, srcs16, row_start, cnt, nb);
    gemm_sage7_kernel<256, 128, 2, true, false, false, true><<<mblk64, 256, 0, stream>>>(
        hA, nb, Wt0s, Wt0n, b0, hB, NN, nullptr);

    // layer 1: h1 [N,256] -> h2 [N,256] (relu)   hA = relu(hB@Ws1 + gather(hB)@Wn1 + b1)
    gather_mean2_kernel<256><<<gblocks, 256, 0, stream>>>(hB, srcs16, row_start, cnt, nb);
    gemm_sage7_kernel<256, 256, 2, true, false, false, true><<<mblk64, 256, 0, stream>>>(
        hB, nb, Wt1s, Wt1n, b1, hA, NN, nullptr);

    // layer 2 (reordered): g = hA@Wn2 (bf16, D=128); nb = gather(g);
    //                      out = hA@Ws2 + b2 + nb   (f32)
    gemm_sage7_kernel<128, 256, 1, false, false, false, false><<<mblk128, 256, 0, stream>>>(
        hA, hA, Wt2n, Wt2n, nullptr, hB, NN, nullptr);
    gather_mean2_kernel<128><<<gblocks, 256, 0, stream>>>(hB, srcs16, row_start, cnt, nb);
    gemm_sage7_kernel<128, 256, 1, false, true, true, true><<<mblk128, 256, 0, stream>>>(
        hA, hA, Wt2s, Wt2s, b2, d_out, NN, nb);
}

// Round 16
// 235.832 us; speedup vs baseline: 1.1650x; 1.1650x over previous
//
#include <hip/hip_runtime.h>

#define NN 50000
#define NE 800000
#define NCHK 200     // edge chunks (NCHK*CHKE == NE exactly)
#define CHKE 4000
#define NBUK 196     // dst>>8 buckets (50000/256 -> 196 covers 50176)
#define BCAP 5120    // per-bucket LDS capacity (mean 4082, sd 64 -> +16 sd)
#define NOFF (NBUK * NCHK)          // 39200
#define NSB  ((NOFF + 255) / 256)   // 154 scan blocks

typedef __attribute__((ext_vector_type(8))) short short8;
typedef __attribute__((ext_vector_type(4))) float f32x4;
typedef unsigned int u32;
typedef unsigned short u16;

__device__ __forceinline__ float bf2f(short u) {
    union { unsigned int i; float f; } c;
    c.i = ((unsigned int)(unsigned short)u) << 16;
    return c.f;
}
__device__ __forceinline__ short f2bf(float f) {
    union { float f; unsigned int i; } c; c.f = f;
    unsigned int u = c.i;
    unsigned int r = (u + 0x7FFFu + ((u >> 16) & 1u)) >> 16;
    return (short)r;
}

// ---------- small utility kernels ----------

__global__ void cvt_f32_bf16_kernel(const float* __restrict__ in, short* __restrict__ out, int n) {
    int gid = blockIdx.x * 256 + threadIdx.x;
    if (gid < n) out[gid] = f2bf(in[gid]);
}

// Weights -> bf16 blobs in REGISTER-FRAGMENT order (for direct coalesced VGPR loads):
// element (k,d):  kt=k>>6, ks=(k>>5)&1, kg=(k>>3)&3, j=k&7, cgp=d>>4, l=d&15
// off = ((((kt*2+ks)*(Dout/16) + cgp)*4 + kg)*16 + l)*8 + j
__global__ void wcvt_all_kernel(const float* __restrict__ Ws0, const float* __restrict__ Wn0,
                                const float* __restrict__ Ws1, const float* __restrict__ Wn1,
                                const float* __restrict__ Ws2, const float* __restrict__ Wn2,
                                short* __restrict__ wts) {
    int gid = blockIdx.x * 256 + threadIdx.x;   // 0..262143
    const float* W; int K, Dout, base, loc;
    if (gid < 65536)       { K = 128; Dout = 256; base = (gid < 32768)  ? 0 : 32768;
                             W = (gid < 32768)  ? Ws0 : Wn0; loc = gid & 32767; }
    else if (gid < 196608) { K = 256; Dout = 256; base = (gid < 131072) ? 65536 : 131072;
                             W = (gid < 131072) ? Ws1 : Wn1; loc = (gid - 65536) & 65535; }
    else                   { K = 256; Dout = 128; base = (gid < 229376) ? 196608 : 229376;
                             W = (gid < 229376) ? Ws2 : Wn2; loc = (gid - 196608) & 32767; }
    int k = loc / Dout, d = loc - k * Dout;
    int kt = k >> 6, ks = (k >> 5) & 1, kg = (k >> 3) & 3, j = k & 7;
    int cgp = d >> 4, l = d & 15;
    int off = ((((kt * 2 + ks) * (Dout >> 4) + cgp) * 4 + kg) * 16 + l) * 8 + j;
    wts[base + off] = f2bf(W[(long)k * Dout + d]);
}

// ---------- bucketed CSR build ----------
__global__ __launch_bounds__(256) void bucket_hist_kernel(const int* __restrict__ dst,
                                                          int* __restrict__ chist) {
    __shared__ int lh[NBUK];
    int b = blockIdx.x, t = threadIdx.x;
    for (int i = t; i < NBUK; i += 256) lh[i] = 0;
    __syncthreads();
    int base = b * CHKE;
    for (int i = t; i < CHKE; i += 256) atomicAdd(&lh[dst[base + i] >> 8], 1);
    __syncthreads();
    for (int i = t; i < NBUK; i += 256) chist[i * NCHK + b] = lh[i];
}

__global__ __launch_bounds__(256) void off_blocksum_kernel(const int* __restrict__ in,
                                                           int* __restrict__ bsum) {
    __shared__ int sm[256];
    int t = threadIdx.x;
    int idx = blockIdx.x * 256 + t;
    sm[t] = (idx < NOFF) ? in[idx] : 0;
    __syncthreads();
    for (int off = 128; off > 0; off >>= 1) {
        if (t < off) sm[t] += sm[t + off];
        __syncthreads();
    }
    if (t == 0) bsum[blockIdx.x] = sm[0];
}

__global__ __launch_bounds__(256) void off_scanb_kernel(const int* __restrict__ bsum,
                                                        int* __restrict__ bpre) {
    __shared__ int sm[256];
    int t = threadIdx.x;
    sm[t] = (t < NSB) ? bsum[t] : 0;
    __syncthreads();
    for (int o = 1; o < 256; o <<= 1) {
        int v = sm[t];
        int a = (t >= o) ? sm[t - o] : 0;
        __syncthreads();
        sm[t] = v + a;
        __syncthreads();
    }
    if (t < NSB) bpre[t] = (t == 0) ? 0 : sm[t - 1];
}

__global__ __launch_bounds__(256) void off_scatter_kernel(const int* __restrict__ in,
                                                          const int* __restrict__ bpre,
                                                          int* __restrict__ off) {
    __shared__ int sm[256];
    int t = threadIdx.x;
    int idx = blockIdx.x * 256 + t;
    int val = (idx < NOFF) ? in[idx] : 0;
    sm[t] = val;
    __syncthreads();
    for (int o = 1; o < 256; o <<= 1) {
        int v = sm[t];
        int a = (t >= o) ? sm[t - o] : 0;
        __syncthreads();
        sm[t] = v + a;
        __syncthreads();
    }
    if (idx < NOFF) off[idx] = bpre[blockIdx.x] + sm[t] - val;   // exclusive
}

__global__ __launch_bounds__(256) void bucket_scatter_kernel(const int* __restrict__ src,
                                                             const int* __restrict__ dst,
                                                             const int* __restrict__ off,
                                                             u32* __restrict__ ebuf) {
    __shared__ int lcur[NBUK];
    int b = blockIdx.x, t = threadIdx.x;
    for (int i = t; i < NBUK; i += 256) lcur[i] = off[i * NCHK + b];
    __syncthreads();
    int base = b * CHKE;
    for (int i = t; i < CHKE; i += 256) {
        int d = dst[base + i], s = src[base + i];
        int slot = atomicAdd(&lcur[d >> 8], 1);
        ebuf[slot] = ((u32)(d & 255) << 16) | (u32)s;
    }
}

__global__ __launch_bounds__(256) void bucket_sort_kernel(const u32* __restrict__ ebuf,
                                                          const int* __restrict__ off,
                                                          u16* __restrict__ srcs16,
                                                          int* __restrict__ row_start,
                                                          int* __restrict__ cnt) {
    __shared__ u32 earr[BCAP];
    __shared__ u16 s16[BCAP];
    __shared__ int lhist[256], lpre[256], lcur[256];
    int k = blockIdx.x, t = threadIdx.x;
    int base = off[k * NCHK];
    int end  = (k < NBUK - 1) ? off[(k + 1) * NCHK] : NE;
    int nE = end - base;
    lhist[t] = 0;
    __syncthreads();
    for (int i = t; i < nE; i += 256) {
        u32 e = ebuf[base + i];
        earr[i] = e;
        atomicAdd(&lhist[e >> 16], 1);
    }
    __syncthreads();
    int v = lhist[t];
    lpre[t] = v;
    __syncthreads();
    for (int o = 1; o < 256; o <<= 1) {
        int x = lpre[t];
        int a = (t >= o) ? lpre[t - o] : 0;
        __syncthreads();
        lpre[t] = x + a;
        __syncthreads();
    }
    int excl = lpre[t] - v;
    int node = k * 256 + t;
    if (node < NN) { row_start[node] = base + excl; cnt[node] = v; }
    lcur[t] = excl;
    __syncthreads();
    for (int i = t; i < nE; i += 256) {
        u32 e = earr[i];
        int pos = atomicAdd(&lcur[e >> 16], 1);
        s16[pos] = (u16)(e & 0xFFFFu);
    }
    __syncthreads();
    for (int i = t; i < nE; i += 256) srcs16[base + i] = s16[i];
}

// ---------- gather-mean: wave per node, EPL edges per load, 16B/lane ----------

template<int D>
__global__ __launch_bounds__(256) void gather_mean2_kernel(
    const short* __restrict__ h, const u16* __restrict__ srcs,
    const int* __restrict__ row_start, const int* __restrict__ cnt,
    short* __restrict__ nb)
{
    constexpr int CPR = D / 8;        // short8 groups per row (16 or 32)
    constexpr int EPL = 64 / CPR;     // edges per wave-load (4 or 2)
    const int wave = threadIdx.x >> 6;
    const int lane = threadIdx.x & 63;
    const int v = blockIdx.x * 4 + wave;
    if (v >= NN) return;
    const int c  = cnt[v];
    const int rs = row_start[v];
    const int slot = lane / CPR;
    const int cg   = lane & (CPR - 1);
    float acc[8];
    #pragma unroll
    for (int j = 0; j < 8; ++j) acc[j] = 0.f;
    const short8* hp = (const short8*)h;
    int i = slot;
    for (; i + 3 * EPL < c; i += 4 * EPL) {
        int s0 = srcs[rs + i];
        int s1 = srcs[rs + i + EPL];
        int s2 = srcs[rs + i + 2 * EPL];
        int s3 = srcs[rs + i + 3 * EPL];
        short8 v0 = hp[(size_t)s0 * CPR + cg];
        short8 v1 = hp[(size_t)s1 * CPR + cg];
        short8 v2 = hp[(size_t)s2 * CPR + cg];
        short8 v3 = hp[(size_t)s3 * CPR + cg];
        #pragma unroll
        for (int j = 0; j < 8; ++j)
            acc[j] += (bf2f(v0[j]) + bf2f(v1[j])) + (bf2f(v2[j]) + bf2f(v3[j]));
    }
    for (; i < c; i += EPL) {
        int s0 = srcs[rs + i];
        short8 v0 = hp[(size_t)s0 * CPR + cg];
        #pragma unroll
        for (int j = 0; j < 8; ++j) acc[j] += bf2f(v0[j]);
    }
    #pragma unroll
    for (int j = 0; j < 8; ++j) {
        if (EPL == 4) acc[j] += __shfl_xor(acc[j], 16);
        acc[j] += __shfl_xor(acc[j], 32);
    }
    if (slot == 0) {
        float inv = (c > 0) ? (1.0f / (float)c) : 0.0f;
        short8 outv;
        #pragma unroll
        for (int j = 0; j < 8; ++j) outv[j] = f2bf(acc[j] * inv);
        ((short8*)nb)[(size_t)v * CPR + cg] = outv;
    }
}

// ---------- fused SAGE layer GEMM v5: small blocks, high blocks/CU ----------
// out = act(A@B0^T [+ Aneigh@B1^T] + bias [+ addin])
// A: [M][KK] bf16 (LDS dbuf, XOR swizzle via pre-swz global source)
// B*: reg-fragment blobs (see wcvt), loaded per (kt,ks) -> 16 transient VGPRs
// 256 threads = 4 waves, wave tile = 64x64.
template<int NOUT, int KK, int PHASES, bool RELU, bool OUT_F32, bool ADDIN, bool BIAS>
__global__ __launch_bounds__(256, 4) void gemm_sage5_kernel(
    const short* __restrict__ Aself, const short* __restrict__ Aneigh,
    const short* __restrict__ Bself, const short* __restrict__ Bneigh,
    const float* __restrict__ bias, void* __restrict__ outp, int M,
    const short* __restrict__ addin)
{
    constexpr int WN = NOUT / 64;          // col wave-groups (4 or 2)
    constexpr int WM = 4 / WN;             // row wave-groups (1 or 2)
    constexpr int BM = 64 * WM;            // 64 or 128
    constexpr int SC = BM / 32;            // stage calls per tile (2 or 4)
    constexpr int MR = 4;                  // 16-row frags per wave
    constexpr int NR = 4;                  // 16-col frags per wave
    constexpr int KT = KK / 64;            // k-tiles per operand
    constexpr int NT = PHASES * KT;        // total tiles
    constexpr int CG = NOUT / 16;          // col-groups in blob

    __shared__ short ldsA[2][BM * 64];     // 2 x (8 or 16) KB

    const int tid  = threadIdx.x;
    const int wave = tid >> 6;
    const int lane = tid & 63;
    const int wm = wave / WN;
    const int wn = wave % WN;
    const int l15 = lane & 15;
    const int kg  = lane >> 4;
    const int bm  = blockIdx.x * BM;

    f32x4 acc[MR][NR];
    #pragma unroll
    for (int a = 0; a < MR; ++a)
        #pragma unroll
        for (int b = 0; b < NR; ++b)
            acc[a][b] = (f32x4){0.f, 0.f, 0.f, 0.f};

    const int srow = tid >> 3;                                // 0..31
    const int scol = ((tid & 7) << 3) ^ ((srow & 7) << 3);    // shorts, pre-swizzled src

    auto stageA = [&](int buf, int t) {
        int ph = t / KT, kt = t - ph * KT;
        const short* A = ph ? Aneigh : Aself;
        #pragma unroll
        for (int c = 0; c < SC; ++c) {
            const short* gp = A + (size_t)(bm + c * 32 + srow) * KK + kt * 64 + scol;
            __builtin_amdgcn_global_load_lds(
                (const __attribute__((address_space(1))) u32*)gp,
                (__attribute__((address_space(3))) u32*)(&ldsA[buf][c * 2048 + (wave << 9)]),
                16, 0, 0);
        }
    };

    stageA(0, 0);
    __syncthreads();

    for (int t = 0; t < NT; ++t) {
        const int cur = t & 1;
        if (t + 1 < NT) stageA(cur ^ 1, t + 1);
        const int ph = t / KT, kt = t - ph * KT;
        const short* __restrict__ Wb = ph ? Bneigh : Bself;

        #pragma unroll
        for (int ks = 0; ks < 2; ++ks) {
            short8 wreg[NR];
            #pragma unroll
            for (int nr = 0; nr < NR; ++nr)
                wreg[nr] = *(const short8*)(
                    Wb + (size_t)((((kt * 2 + ks) * CG + wn * NR + nr) * 4 + kg) * 16 + l15) * 8);
            short8 areg[MR];
            #pragma unroll
            for (int mr = 0; mr < MR; ++mr) {
                int r = wm * 64 + mr * 16 + l15;
                areg[mr] = *(const short8*)(&ldsA[cur][r * 64 + ((ks * 32 + kg * 8) ^ ((r & 7) << 3))]);
            }
            #pragma unroll
            for (int mr = 0; mr < MR; ++mr)
                #pragma unroll
                for (int nr = 0; nr < NR; ++nr)
                    acc[mr][nr] = __builtin_amdgcn_mfma_f32_16x16x32_bf16(
                        areg[mr], wreg[nr], acc[mr][nr], 0, 0, 0);
        }
        __syncthreads();
    }

    // epilogue
    #pragma unroll
    for (int mr = 0; mr < MR; ++mr) {
        int rowb = bm + wm * 64 + mr * 16 + kg * 4;
        #pragma unroll
        for (int nr = 0; nr < NR; ++nr) {
            int col = wn * 64 + nr * 16 + l15;
            float bv = BIAS ? bias[col] : 0.f;
            #pragma unroll
            for (int r = 0; r < 4; ++r) {
                int row = rowb + r;
                if (row < M) {
                    float vv = acc[mr][nr][r] + bv;
                    if (ADDIN) vv += bf2f(addin[(size_t)row * NOUT + col]);
                    if (RELU) vv = fmaxf(vv, 0.f);
                    if (OUT_F32) ((float*)outp)[(size_t)row * NOUT + col] = vv;
                    else         ((short*)outp)[(size_t)row * NOUT + col] = f2bf(vv);
                }
            }
        }
    }
}

// ---------- launch ----------

extern "C" void kernel_launch(void* const* d_in, const int* in_sizes, int n_in,
                              void* d_out, int out_size, void* d_ws, size_t ws_size,
                              hipStream_t stream) {
    const float* x    = (const float*)d_in[0];
    const int*   srcp = (const int*)d_in[1];
    const int*   dstp = (const int*)d_in[2];
    const float* Ws0  = (const float*)d_in[3];
    const float* Wn0  = (const float*)d_in[4];
    const float* b0   = (const float*)d_in[5];
    const float* Ws1  = (const float*)d_in[6];
    const float* Wn1  = (const float*)d_in[7];
    const float* b1   = (const float*)d_in[8];
    const float* Ws2  = (const float*)d_in[9];
    const float* Wn2  = (const float*)d_in[10];
    const float* b2   = (const float*)d_in[11];

    char* base = (char*)d_ws;
    size_t off_b = 0;
    auto alloc = [&](size_t bytes) -> void* {
        void* p = base + off_b;
        off_b += (bytes + 255) & ~(size_t)255;
        return p;
    };

    int*   cnt       = (int*)alloc((size_t)NN * 4);
    int*   row_start = (int*)alloc((size_t)NN * 4);
    int*   chist     = (int*)alloc((size_t)NOFF * 4);
    int*   offb      = (int*)alloc((size_t)NOFF * 4);
    int*   bsum      = (int*)alloc((size_t)NSB * 4);
    int*   bpre      = (int*)alloc((size_t)NSB * 4);
    u32*   ebuf      = (u32*)alloc((size_t)NE * 4);
    u16*   srcs16    = (u16*)alloc((size_t)NE * 2);
    short* hA        = (short*)alloc((size_t)NN * 256 * 2);
    short* hB        = (short*)alloc((size_t)NN * 256 * 2);
    short* nb        = (short*)alloc((size_t)NN * 256 * 2);
    short* wts       = (short*)alloc((size_t)262144 * 2 + 131072);
    short* Wt0s = wts;            // blobs, see wcvt_all_kernel
    short* Wt0n = Wt0s + 32768;
    short* Wt1s = Wt0n + 32768;
    short* Wt1n = Wt1s + 65536;
    short* Wt2s = Wt1n + 65536;
    short* Wt2n = Wt2s + 32768;

    // CSR build: bucketed counting sort (XCD-local final scatter)
    bucket_hist_kernel<<<NCHK, 256, 0, stream>>>(dstp, chist);
    off_blocksum_kernel<<<NSB, 256, 0, stream>>>(chist, bsum);
    off_scanb_kernel<<<1, 256, 0, stream>>>(bsum, bpre);
    off_scatter_kernel<<<NSB, 256, 0, stream>>>(chist, bpre, offb);
    bucket_scatter_kernel<<<NCHK, 256, 0, stream>>>(srcp, dstp, offb, ebuf);
    bucket_sort_kernel<<<NBUK, 256, 0, stream>>>(ebuf, offb, srcs16, row_start, cnt);

    // weight conversion -> reg-fragment bf16 blobs, single launch
    wcvt_all_kernel<<<1024, 256, 0, stream>>>(Ws0, Wn0, Ws1, Wn1, Ws2, Wn2, wts);

    // x -> bf16
    cvt_f32_bf16_kernel<<<(NN * 128 + 255) / 256, 256, 0, stream>>>(x, hA, NN * 128);

    const int mblk64  = (NN + 63) / 64;     // 782 (NOUT=256 path, BM=64)
    const int mblk128 = (NN + 127) / 128;   // 391 (NOUT=128 path, BM=128)
    const int gblocks = (NN + 3) / 4;       // 12500

    // layer 0: h0 [N,128] -> h1 [N,256] (relu)   hB = relu(hA@Ws0 + gather(hA)@Wn0 + b0)
    gather_mean2_kernel<128><<<gblocks, 256, 0, stream>>>(hA, srcs16, row_start, cnt, nb);
    gemm_sage5_kernel<256, 128, 2, true, false, false, true><<<mblk64, 256, 0, stream>>>(
        hA, nb, Wt0s, Wt0n, b0, hB, NN, nullptr);

    // layer 1: h1 [N,256] -> h2 [N,256] (relu)   hA = relu(hB@Ws1 + gather(hB)@Wn1 + b1)
    gather_mean2_kernel<256><<<gblocks, 256, 0, stream>>>(hB, srcs16, row_start, cnt, nb);
    gemm_sage5_kernel<256, 256, 2, true, false, false, true><<<mblk64, 256, 0, stream>>>(
        hB, nb, Wt1s, Wt1n, b1, hA, NN, nullptr);

    // layer 2 (reordered): g = hA@Wn2 (bf16, D=128); nb = gather(g);
    //                      out = hA@Ws2 + b2 + nb   (f32)
    gemm_sage5_kernel<128, 256, 1, false, false, false, false><<<mblk128, 256, 0, stream>>>(
        hA, hA, Wt2n, Wt2n, nullptr, hB, NN, nullptr);
    gather_mean2_kernel<128><<<gblocks, 256, 0, stream>>>(hB, srcs16, row_start, cnt, nb);
    gemm_sage5_kernel<128, 256, 1, false, true, true, true><<<mblk128, 256, 0, stream>>>(
        hA, hA, Wt2s, Wt2s, b2, d_out, NN, nb);
}